// Round 5
// baseline (115.634 us; speedup 1.0000x reference)
//
#include <hip/hip_runtime.h>
#include <math.h>

#define SEQ_LEN   8192
#define HIDDEN    1024
#define NUM_SPANS 4096
#define MAX_W     32
#define NBLK3     512               // main kernel: 8 spans per 512-thread block
#define NXCD      8

typedef float f4v __attribute__((ext_vector_type(4)));

__device__ __forceinline__ float dot4(float4 a, float4 b) {
    return a.x * b.x + a.y * b.y + a.z * b.z + a.w * b.w;
}

// Non-temporal 16B store: output (50 MB) is never re-read; keep it out of
// L2/L3 so embedding rows stay resident.
__device__ __forceinline__ void nt_store4(float4* p, float4 v) {
    f4v x = { v.x, v.y, v.z, v.w };
    __builtin_nontemporal_store(x, (f4v*)p);
}

// ---------------------------------------------------------------------------
// Prep kernel (unchanged from round 4 -- both its levers verified):
//   * sort block at blockIdx 0 (starts in the first dispatch round);
//   * score blocks XCD-aligned with main's row usage, so prep's compulsory
//     33.5 MB table read pre-warms exactly the L2 each XCD's main blocks
//     will re-read.
// Scores are span-invariant: one wave computes dot(emb[row], attn_w) + bias.
// ---------------------------------------------------------------------------
__global__ __launch_bounds__(1024) void prep_kernel(
    const int* __restrict__ starts,
    const float* __restrict__ emb,
    const float* __restrict__ attn_w,
    const float* __restrict__ attn_b,
    int* __restrict__ perm,             // (NUM_SPANS,)
    float* __restrict__ scores)         // (SEQ_LEN,)
{
    const int tid  = threadIdx.x;
    const int lane = tid & 63;
    const int wid  = tid >> 6;

    if (blockIdx.x != 0) {
        const int x = blockIdx.x & 7;                       // this block's XCD
        const int k = (blockIdx.x >> 3) - (x == 0 ? 1 : 0); // chunk in XCD range
        const int row = x * 1024 + k * 16 + wid;            // 16 rows per block
        const float4* __restrict__ wv4 = (const float4*)attn_w;
        const float4 wv0 = wv4[lane];
        const float4 wv1 = wv4[lane + 64];
        const float4 wv2 = wv4[lane + 128];
        const float4 wv3 = wv4[lane + 192];
        const float4* __restrict__ rp = (const float4*)emb + (size_t)row * 256;
        float p = dot4(rp[lane],       wv0) + dot4(rp[lane + 64],  wv1)
                + dot4(rp[lane + 128], wv2) + dot4(rp[lane + 192], wv3);
        #pragma unroll
        for (int off = 32; off > 0; off >>= 1)
            p += __shfl_xor(p, off, 64);
        if (lane == 0) scores[row] = p + attn_b[0];
        return;
    }

    // ---- blockIdx 0: counting sort of span ids by start (1024 buckets) ----
    __shared__ int hist[1024];
    __shared__ int base[1024];
    __shared__ int wsum[16];

    hist[tid] = 0;
    __syncthreads();

    #pragma unroll
    for (int i = tid; i < NUM_SPANS; i += 1024)
        atomicAdd(&hist[starts[i] >> 3], 1);
    __syncthreads();

    const int v = hist[tid];
    int sc = v;
    #pragma unroll
    for (int off = 1; off < 64; off <<= 1) {
        const int t = __shfl_up(sc, off, 64);
        if (lane >= off) sc += t;
    }
    if (lane == 63) wsum[wid] = sc;
    __syncthreads();
    if (wid == 0 && lane < 16) {
        int ws = wsum[lane];
        #pragma unroll
        for (int off = 1; off < 16; off <<= 1) {
            const int t = __shfl_up(ws, off, 64);
            if (lane >= off) ws += t;
        }
        wsum[lane] = ws;
    }
    __syncthreads();
    const int waveOff = (wid == 0) ? 0 : wsum[wid - 1];
    base[tid] = waveOff + sc - v;
    __syncthreads();

    hist[tid] = 0;
    __syncthreads();

    #pragma unroll
    for (int i = tid; i < NUM_SPANS; i += 1024) {
        const int b   = starts[i] >> 3;
        const int pos = base[b] + atomicAdd(&hist[b], 1);
        perm[pos] = i;
    }
}

// ---------------------------------------------------------------------------
// Main kernel, round 5: ROW-SYNCHRONIZED span grouping.
// Round-4 evidence: with 2048 co-resident blocks the per-wave critical path
// is ~2 us but the kernel measures ~22 us -> L2-throughput-bound on the 8x
// redundant row reads (67K logical row-reads vs 8.2K unique rows, ~270 MB).
// New shape: 512-thread block = 8 waves = 8 CONSECUTIVE sorted spans, one
// full span per wave (lane c owns cols {4c..4c+3} x4). All waves sweep a
// common absolute row window from t0 = bucket-aligned first start: at step t
// every wave reads row t -> one L2 fetch + 7 L1 broadcast hits. Unique
// reads/block ~31 rows vs 8x17 before => L2 read traffic /4. Steps outside a
// wave's span get weight 0 via cndmask (no divergence); start/end rows are
// captured by wave-uniform t==start / t==end branches (no extra fetches).
// No LDS, no barriers; waves stay time-aligned by symmetry.
// launch_bounds(512,4): grid gives 2 blocks/CU (16 waves/CU) anyway; the
// 128-VGPR cap makes the 1-deep prefetch spill-proof.
// ---------------------------------------------------------------------------
__global__ __launch_bounds__(512, 4) void span_repr_kernel(
    const float* __restrict__ emb,      // (SEQ_LEN, HIDDEN)
    const int* __restrict__ starts,     // (NUM_SPANS,)
    const int* __restrict__ ends,       // (NUM_SPANS,)
    const int* __restrict__ perm,       // (NUM_SPANS,) sorted span order
    const float* __restrict__ scores,   // (SEQ_LEN,) precomputed row scores
    float* __restrict__ out)            // (NUM_SPANS, 3*HIDDEN)
{
    const int tid = threadIdx.x;
    const int wid = tid >> 6;           // wave 0..7 -> span within block
    const int c   = tid & 63;           // lane

    // XCD-contiguous sorted slot; 8 consecutive sorted spans per block
    const int slot = (blockIdx.x & (NXCD - 1)) * (NBLK3 / NXCD) + (blockIdx.x >> 3);
    const int s    = perm[(slot << 3) + wid];

    const int start = starts[s];
    const int end   = ends[s];
    const int wmax  = end - start;      // inclusive width-1, 0..31

    // Common window start: sort buckets are 8 rows wide, and the block's
    // first sorted span has the smallest bucket -> its bucket base is a safe
    // lower bound for every span start in the block (at most 7 early steps,
    // each weight-0 and L1-shared).
    const int t0 = starts[perm[slot << 3]] & ~7;

    // ---- softmax weights from precomputed scores (outside the row loop) ----
    const float sc = (c <= wmax) ? scores[start + c] : -INFINITY;
    float mx = sc;
    #pragma unroll
    for (int off = 32; off > 0; off >>= 1)
        mx = fmaxf(mx, __shfl_xor(mx, off, 64));
    const float e = (c <= wmax) ? __expf(sc - mx) : 0.0f;
    float sum = e;
    #pragma unroll
    for (int off = 32; off > 0; off >>= 1)
        sum += __shfl_xor(sum, off, 64);
    const float wt = e / sum;           // lane c: weight of span row c

    const float4* __restrict__ embr = (const float4*)emb;
    float4* __restrict__ out4 = (float4*)(out + (size_t)s * (3 * HIDDEN));

    float4 a0 = make_float4(0.f, 0.f, 0.f, 0.f);
    float4 a1 = make_float4(0.f, 0.f, 0.f, 0.f);
    float4 a2 = make_float4(0.f, 0.f, 0.f, 0.f);
    float4 a3 = make_float4(0.f, 0.f, 0.f, 0.f);

    // 1-deep register pipeline over the common row window
    const float4* rp = embr + (size_t)t0 * 256;
    float4 v0 = rp[c];
    float4 v1 = rp[c + 64];
    float4 v2 = rp[c + 128];
    float4 v3 = rp[c + 192];

    for (int t = t0; t <= end; ++t) {
        const float4* __restrict__ np = embr + (size_t)min(t + 1, end) * 256;
        float4 n0 = np[c];
        float4 n1 = np[c + 64];
        float4 n2 = np[c + 128];
        float4 n3 = np[c + 192];
        __builtin_amdgcn_sched_barrier(0);   // pin loads above the compute

        // weight of absolute row t for this wave's span (0 outside the span;
        // t <= end guarantees rr <= wmax, only rr < 0 needs masking)
        const int rr = t - start;
        float wr = __shfl(wt, max(rr, 0), 64);
        wr = (rr >= 0) ? wr : 0.0f;

        a0.x += wr * v0.x; a0.y += wr * v0.y; a0.z += wr * v0.z; a0.w += wr * v0.w;
        a1.x += wr * v1.x; a1.y += wr * v1.y; a1.z += wr * v1.z; a1.w += wr * v1.w;
        a2.x += wr * v2.x; a2.y += wr * v2.y; a2.z += wr * v2.z; a2.w += wr * v2.w;
        a3.x += wr * v3.x; a3.y += wr * v3.y; a3.z += wr * v3.z; a3.w += wr * v3.w;

        if (t == start) {                    // wave-uniform, taken once
            nt_store4(&out4[c],       v0);
            nt_store4(&out4[c + 64],  v1);
            nt_store4(&out4[c + 128], v2);
            nt_store4(&out4[c + 192], v3);
        }

        v0 = n0; v1 = n1; v2 = n2; v3 = n3;
    }

    // v holds row `end` (last prefetch clamps to end)
    nt_store4(&out4[256 + c],       v0);
    nt_store4(&out4[256 + c + 64],  v1);
    nt_store4(&out4[256 + c + 128], v2);
    nt_store4(&out4[256 + c + 192], v3);

    // weights pre-normalized -> acc is the final attention output
    nt_store4(&out4[512 + c],       a0);
    nt_store4(&out4[512 + c + 64],  a1);
    nt_store4(&out4[512 + c + 128], a2);
    nt_store4(&out4[512 + c + 192], a3);
}

extern "C" void kernel_launch(void* const* d_in, const int* in_sizes, int n_in,
                              void* d_out, int out_size, void* d_ws, size_t ws_size,
                              hipStream_t stream) {
    const float* emb    = (const float*)d_in[0];
    const int*   starts = (const int*)d_in[1];
    const int*   ends   = (const int*)d_in[2];
    const float* attn_w = (const float*)d_in[3];
    const float* attn_b = (const float*)d_in[4];
    float* out = (float*)d_out;

    int*   perm   = (int*)d_ws;                        // 4096 ints  = 16 KB
    float* scores = (float*)((int*)d_ws + NUM_SPANS);  // 8192 floats = 32 KB

    prep_kernel<<<513, 1024, 0, stream>>>(starts, emb, attn_w, attn_b, perm, scores);
    span_repr_kernel<<<NBLK3, 512, 0, stream>>>(emb, starts, ends, perm, scores, out);
}

// Round 6
// 115.024 us; speedup vs baseline: 1.0053x; 1.0053x over previous
//
#include <hip/hip_runtime.h>
#include <math.h>

#define SEQ_LEN   8192
#define HIDDEN    1024
#define NUM_SPANS 4096
#define MAX_W     32
#define NBLK2     2048              // main kernel: 2 spans per block
#define NXCD      8

typedef float f4v __attribute__((ext_vector_type(4)));

__device__ __forceinline__ float dot4(float4 a, float4 b) {
    return a.x * b.x + a.y * b.y + a.z * b.z + a.w * b.w;
}

// Non-temporal 16B store: output (50 MB) is never re-read; keep it out of
// L2/L3 so embedding rows stay resident.
__device__ __forceinline__ void nt_store4(float4* p, float4 v) {
    f4v x = { v.x, v.y, v.z, v.w };
    __builtin_nontemporal_store(x, (f4v*)p);
}

// ---------------------------------------------------------------------------
// Prep kernel (round-4 structure, verified):
//   * block 0: counting sort of spans by start (1024 buckets of 8 rows).
//     Round-6 tweak: emit SoA sorted metadata (sid/sstart/send) so the main
//     kernel's preamble has 3 independent loads instead of the dependent
//     chain perm[i] -> starts[perm[i]] (two serialized gather levels).
//   * blocks 1..512: scores[row] = dot(emb[row], attn_w) + bias, one wave
//     per row, XCD-ALIGNED with main's row usage (main gives XCD x sorted
//     spans [512x,512(x+1)) -> rows ~[1024x,1024(x+1)); score block for
//     chunk k of XCD-range x sits at blockIdx%8==x), so prep's compulsory
//     33.5 MB table read pre-warms exactly the right L2s. Verified round 4.
// NOTE (round-5 post-mortem): row-synchronized span grouping REGRESSED
// (107.6 -> 115.6 us) -- window padding + halved occupancy outweighed the
// redundancy cut. Main is not L2-throughput-bound; do not retry.
// ---------------------------------------------------------------------------
__global__ __launch_bounds__(1024) void prep_kernel(
    const int* __restrict__ starts,
    const int* __restrict__ ends,
    const float* __restrict__ emb,
    const float* __restrict__ attn_w,
    const float* __restrict__ attn_b,
    int* __restrict__ sid,              // (NUM_SPANS,) sorted span ids
    int* __restrict__ sstart,           // (NUM_SPANS,) sorted starts
    int* __restrict__ send,             // (NUM_SPANS,) sorted ends
    float* __restrict__ scores)         // (SEQ_LEN,)
{
    const int tid  = threadIdx.x;
    const int lane = tid & 63;
    const int wid  = tid >> 6;

    if (blockIdx.x != 0) {
        const int x = blockIdx.x & 7;                       // this block's XCD
        const int k = (blockIdx.x >> 3) - (x == 0 ? 1 : 0); // chunk in XCD range
        const int row = x * 1024 + k * 16 + wid;            // 16 rows per block
        const float4* __restrict__ wv4 = (const float4*)attn_w;
        const float4 wv0 = wv4[lane];
        const float4 wv1 = wv4[lane + 64];
        const float4 wv2 = wv4[lane + 128];
        const float4 wv3 = wv4[lane + 192];
        const float4* __restrict__ rp = (const float4*)emb + (size_t)row * 256;
        float p = dot4(rp[lane],       wv0) + dot4(rp[lane + 64],  wv1)
                + dot4(rp[lane + 128], wv2) + dot4(rp[lane + 192], wv3);
        #pragma unroll
        for (int off = 32; off > 0; off >>= 1)
            p += __shfl_xor(p, off, 64);
        if (lane == 0) scores[row] = p + attn_b[0];
        return;
    }

    // ---- blockIdx 0: counting sort of span ids by start (1024 buckets) ----
    __shared__ int hist[1024];
    __shared__ int base[1024];
    __shared__ int wsum[16];

    hist[tid] = 0;
    __syncthreads();

    #pragma unroll
    for (int i = tid; i < NUM_SPANS; i += 1024)
        atomicAdd(&hist[starts[i] >> 3], 1);
    __syncthreads();

    const int v = hist[tid];
    int sc = v;
    #pragma unroll
    for (int off = 1; off < 64; off <<= 1) {
        const int t = __shfl_up(sc, off, 64);
        if (lane >= off) sc += t;
    }
    if (lane == 63) wsum[wid] = sc;
    __syncthreads();
    if (wid == 0 && lane < 16) {
        int ws = wsum[lane];
        #pragma unroll
        for (int off = 1; off < 16; off <<= 1) {
            const int t = __shfl_up(ws, off, 64);
            if (lane >= off) ws += t;
        }
        wsum[lane] = ws;                 // inclusive wave sums
    }
    __syncthreads();
    const int waveOff = (wid == 0) ? 0 : wsum[wid - 1];
    base[tid] = waveOff + sc - v;        // exclusive prefix for bucket tid
    __syncthreads();

    hist[tid] = 0;                       // reuse as per-bucket counters
    __syncthreads();

    #pragma unroll
    for (int i = tid; i < NUM_SPANS; i += 1024) {
        const int st  = starts[i];
        const int b   = st >> 3;
        const int pos = base[b] + atomicAdd(&hist[b], 1);
        sid[pos]    = i;
        sstart[pos] = st;
        send[pos]   = ends[i];
    }
}

// ---------------------------------------------------------------------------
// Main kernel (round-4 optimum, reverted): two waves per span (each owns 512
// columns), 2 spans per block -> 2048 blocks, 32 waves/CU. Sorted span order
// + XCD-contiguous slot mapping keeps each XCD's working set ~4.2 MB in its
// private L2 (pre-warmed by prep). Softmax weights computed once before the
// row loop from precomputed scores; the row loop is
//   load 2xfloat4, wr = broadcast(wt, r), acc += wr * v
// with a 1-deep register pipeline -- no LDS, no barriers.
// ---------------------------------------------------------------------------
__global__ __launch_bounds__(256, 8) void span_repr_kernel(
    const float* __restrict__ emb,      // (SEQ_LEN, HIDDEN)
    const int* __restrict__ sid,        // (NUM_SPANS,) sorted span ids
    const int* __restrict__ sstart,     // (NUM_SPANS,) sorted starts
    const int* __restrict__ send,       // (NUM_SPANS,) sorted ends
    const float* __restrict__ scores,   // (SEQ_LEN,) precomputed row scores
    float* __restrict__ out)            // (NUM_SPANS, 3*HIDDEN)
{
    const int tid = threadIdx.x;
    const int w2  = tid >> 6;           // wave id 0..3
    const int c   = tid & 63;           // lane

    // XCD-contiguous sorted slot; 2 spans per block, wave pair per span
    const int slot = (blockIdx.x & (NXCD - 1)) * (NBLK2 / NXCD) + (blockIdx.x >> 3);
    const int idx  = (slot << 1) + (w2 >> 1);
    const int h    = w2 & 1;            // column half: f4 indices h*128 + [0,128)

    // three INDEPENDENT loads (SoA) -- no perm->starts dependent chain
    const int s     = sid[idx];
    const int start = sstart[idx];
    const int wmax  = send[idx] - start;  // inclusive width-1, 0..31

    // ---- softmax weights from precomputed scores (outside the row loop) ----
    const float sc = (c <= wmax) ? scores[start + c] : -INFINITY;  // wmax<32
    float mx = sc;
    #pragma unroll
    for (int off = 32; off > 0; off >>= 1)
        mx = fmaxf(mx, __shfl_xor(mx, off, 64));
    const float e = (c <= wmax) ? __expf(sc - mx) : 0.0f;
    float sum = e;
    #pragma unroll
    for (int off = 32; off > 0; off >>= 1)
        sum += __shfl_xor(sum, off, 64);
    const float wt = e / sum;           // lane c: weight of span row c

    const float4* __restrict__ embr = (const float4*)emb + (size_t)start * 256 + (h << 7);
    float4* __restrict__ out4 = (float4*)(out + (size_t)s * (3 * HIDDEN)) + (h << 7);

    // row 0 == start row
    float4 v0 = embr[c];
    float4 v1 = embr[c + 64];
    nt_store4(&out4[c],      v0);
    nt_store4(&out4[c + 64], v1);

    const float w0 = __shfl(wt, 0, 64);
    float4 a0 = make_float4(w0 * v0.x, w0 * v0.y, w0 * v0.z, w0 * v0.w);
    float4 a1 = make_float4(w0 * v1.x, w0 * v1.y, w0 * v1.z, w0 * v1.w);

    // 1-deep pipeline; p enters holding row min(1,wmax) so that after the
    // loop p always holds row wmax (== end row), including wmax==0.
    const float4* nr = embr + (size_t)min(1, wmax) * 256;
    float4 p0 = nr[c];
    float4 p1 = nr[c + 64];

    for (int r = 1; r <= wmax; ++r) {
        const float4* __restrict__ xr = embr + (size_t)min(r + 1, wmax) * 256;
        float4 n0 = xr[c];
        float4 n1 = xr[c + 64];
        __builtin_amdgcn_sched_barrier(0);   // pin loads above the compute

        const float wr = __shfl(wt, r, 64);
        a0.x += wr * p0.x; a0.y += wr * p0.y; a0.z += wr * p0.z; a0.w += wr * p0.w;
        a1.x += wr * p1.x; a1.y += wr * p1.y; a1.z += wr * p1.z; a1.w += wr * p1.w;

        p0 = n0; p1 = n1;
    }

    // p holds row wmax == end row
    nt_store4(&out4[256 + c],      p0);
    nt_store4(&out4[256 + c + 64], p1);

    // weights are pre-normalized -> acc is the final attention output
    nt_store4(&out4[512 + c],      a0);
    nt_store4(&out4[512 + c + 64], a1);
}

extern "C" void kernel_launch(void* const* d_in, const int* in_sizes, int n_in,
                              void* d_out, int out_size, void* d_ws, size_t ws_size,
                              hipStream_t stream) {
    const float* emb    = (const float*)d_in[0];
    const int*   starts = (const int*)d_in[1];
    const int*   ends   = (const int*)d_in[2];
    const float* attn_w = (const float*)d_in[3];
    const float* attn_b = (const float*)d_in[4];
    float* out = (float*)d_out;

    int*   sid    = (int*)d_ws;                        // 4096 ints = 16 KB
    int*   sstart = sid + NUM_SPANS;                   // 16 KB
    int*   send   = sstart + NUM_SPANS;                // 16 KB
    float* scores = (float*)(send + NUM_SPANS);        // 8192 floats = 32 KB

    prep_kernel<<<513, 1024, 0, stream>>>(starts, ends, emb, attn_w, attn_b,
                                          sid, sstart, send, scores);
    span_repr_kernel<<<NBLK2, 256, 0, stream>>>(emb, sid, sstart, send, scores, out);
}

// Round 8
// 109.635 us; speedup vs baseline: 1.0547x; 1.0492x over previous
//
#include <hip/hip_runtime.h>
#include <math.h>

#define SEQ_LEN   8192
#define HIDDEN    1024
#define NUM_SPANS 4096
#define MAX_W     32
#define NBLK2     2048              // main kernel: 2 spans per block
#define NXCD      8

typedef float f4v __attribute__((ext_vector_type(4)));

__device__ __forceinline__ float dot4(float4 a, float4 b) {
    return a.x * b.x + a.y * b.y + a.z * b.z + a.w * b.w;
}

// Non-temporal 16B store: output (50 MB) is never re-read; keep it out of
// L2/L3 so embedding rows stay resident.
__device__ __forceinline__ void nt_store4(float4* p, float4 v) {
    f4v x = { v.x, v.y, v.z, v.w };
    __builtin_nontemporal_store(x, (f4v*)p);
}

// ---------------------------------------------------------------------------
// FINAL (round-4 verified optimum, 107.6 us; series noise band +-4 us).
// Round 7 was an infrastructure failure (container acquisition), not a
// kernel failure -- identical source resubmitted.
// Structure and evidence trail:
//   * counting sort of spans by start (block 0, first dispatch round) --
//     round 2: fixed L2 locality of the span->row gather, 48 -> ~30 us main.
//   * scores[row] = dot(emb[row], attn_w) + bias precomputed once (round
//     3): span-invariant, deletes dot+butterfly+exp from the row loop.
//   * score blocks XCD-ALIGNED with main's row usage (round 4, -4 us): main
//     gives XCD x sorted spans [512x,512(x+1)) -> rows ~[1024x,1024(x+1));
//     placing row-chunk k of XCD-range x at blockIdx%8==x makes prep's
//     compulsory 33.5 MB read pre-warm exactly the right private L2.
//   * main: 2 waves/span, 2 spans/block, 2048 blocks = 32 waves/CU; weights
//     finalized before the row loop; 1-deep register pipeline; NT stores.
// Refuted branches (do not retry): row-synchronized span grouping (round 5,
// +8 us: window padding + halved occupancy beat the redundancy cut); SoA
// sorted metadata (round 6: within noise, no provable gain).
// Floor accounting: ~85 us fixed harness fills + prep 5.3 us table read +
// main ~14-18 us (50 MB NT writes + warm-L2 reads) + launch gaps -- measured
// controllable share sits within a few percent of this; remaining deltas are
// below the +-4 us run-to-run noise.
// ---------------------------------------------------------------------------
__global__ __launch_bounds__(1024) void prep_kernel(
    const int* __restrict__ starts,
    const float* __restrict__ emb,
    const float* __restrict__ attn_w,
    const float* __restrict__ attn_b,
    int* __restrict__ perm,             // (NUM_SPANS,)
    float* __restrict__ scores)         // (SEQ_LEN,)
{
    const int tid  = threadIdx.x;
    const int lane = tid & 63;
    const int wid  = tid >> 6;

    if (blockIdx.x != 0) {
        // ---- scores: one wave per row, XCD-aligned row mapping ----
        const int x = blockIdx.x & 7;                       // this block's XCD
        const int k = (blockIdx.x >> 3) - (x == 0 ? 1 : 0); // chunk in XCD range
        const int row = x * 1024 + k * 16 + wid;            // 16 rows per block
        const float4* __restrict__ wv4 = (const float4*)attn_w;
        const float4 wv0 = wv4[lane];
        const float4 wv1 = wv4[lane + 64];
        const float4 wv2 = wv4[lane + 128];
        const float4 wv3 = wv4[lane + 192];
        const float4* __restrict__ rp = (const float4*)emb + (size_t)row * 256;
        float p = dot4(rp[lane],       wv0) + dot4(rp[lane + 64],  wv1)
                + dot4(rp[lane + 128], wv2) + dot4(rp[lane + 192], wv3);
        #pragma unroll
        for (int off = 32; off > 0; off >>= 1)
            p += __shfl_xor(p, off, 64);
        if (lane == 0) scores[row] = p + attn_b[0];
        return;
    }

    // ---- blockIdx 0: counting sort of span ids by start (1024 buckets) ----
    __shared__ int hist[1024];
    __shared__ int base[1024];
    __shared__ int wsum[16];

    hist[tid] = 0;
    __syncthreads();

    #pragma unroll
    for (int i = tid; i < NUM_SPANS; i += 1024)
        atomicAdd(&hist[starts[i] >> 3], 1);
    __syncthreads();

    const int v = hist[tid];
    int sc = v;
    #pragma unroll
    for (int off = 1; off < 64; off <<= 1) {
        const int t = __shfl_up(sc, off, 64);
        if (lane >= off) sc += t;
    }
    if (lane == 63) wsum[wid] = sc;
    __syncthreads();
    if (wid == 0 && lane < 16) {
        int ws = wsum[lane];
        #pragma unroll
        for (int off = 1; off < 16; off <<= 1) {
            const int t = __shfl_up(ws, off, 64);
            if (lane >= off) ws += t;
        }
        wsum[lane] = ws;                 // inclusive wave sums
    }
    __syncthreads();
    const int waveOff = (wid == 0) ? 0 : wsum[wid - 1];
    base[tid] = waveOff + sc - v;        // exclusive prefix for bucket tid
    __syncthreads();

    hist[tid] = 0;                       // reuse as per-bucket counters
    __syncthreads();

    #pragma unroll
    for (int i = tid; i < NUM_SPANS; i += 1024) {
        const int b   = starts[i] >> 3;
        const int pos = base[b] + atomicAdd(&hist[b], 1);
        perm[pos] = i;
    }
}

__global__ __launch_bounds__(256, 8) void span_repr_kernel(
    const float* __restrict__ emb,      // (SEQ_LEN, HIDDEN)
    const int* __restrict__ starts,     // (NUM_SPANS,)
    const int* __restrict__ ends,       // (NUM_SPANS,)
    const int* __restrict__ perm,       // (NUM_SPANS,) sorted span order
    const float* __restrict__ scores,   // (SEQ_LEN,) precomputed row scores
    float* __restrict__ out)            // (NUM_SPANS, 3*HIDDEN)
{
    const int tid = threadIdx.x;
    const int w2  = tid >> 6;           // wave id 0..3
    const int c   = tid & 63;           // lane

    // XCD-contiguous sorted slot; 2 spans per block, wave pair per span
    const int slot = (blockIdx.x & (NXCD - 1)) * (NBLK2 / NXCD) + (blockIdx.x >> 3);
    const int s    = perm[(slot << 1) + (w2 >> 1)];
    const int h    = w2 & 1;            // column half: f4 indices h*128 + [0,128)

    const int start = starts[s];
    const int wmax  = ends[s] - start;  // inclusive width-1, 0..31

    // ---- softmax weights from precomputed scores (outside the row loop) ----
    const float sc = (c <= wmax) ? scores[start + c] : -INFINITY;  // wmax<32
    float mx = sc;
    #pragma unroll
    for (int off = 32; off > 0; off >>= 1)
        mx = fmaxf(mx, __shfl_xor(mx, off, 64));
    const float e = (c <= wmax) ? __expf(sc - mx) : 0.0f;
    float sum = e;
    #pragma unroll
    for (int off = 32; off > 0; off >>= 1)
        sum += __shfl_xor(sum, off, 64);
    const float wt = e / sum;           // lane c: weight of span row c

    const float4* __restrict__ embr = (const float4*)emb + (size_t)start * 256 + (h << 7);
    float4* __restrict__ out4 = (float4*)(out + (size_t)s * (3 * HIDDEN)) + (h << 7);

    // row 0 == start row
    float4 v0 = embr[c];
    float4 v1 = embr[c + 64];
    nt_store4(&out4[c],      v0);
    nt_store4(&out4[c + 64], v1);

    const float w0 = __shfl(wt, 0, 64);
    float4 a0 = make_float4(w0 * v0.x, w0 * v0.y, w0 * v0.z, w0 * v0.w);
    float4 a1 = make_float4(w0 * v1.x, w0 * v1.y, w0 * v1.z, w0 * v1.w);

    // 1-deep pipeline; p enters holding row min(1,wmax) so that after the
    // loop p always holds row wmax (== end row), including wmax==0.
    const float4* nr = embr + (size_t)min(1, wmax) * 256;
    float4 p0 = nr[c];
    float4 p1 = nr[c + 64];

    for (int r = 1; r <= wmax; ++r) {
        const float4* __restrict__ xr = embr + (size_t)min(r + 1, wmax) * 256;
        float4 n0 = xr[c];
        float4 n1 = xr[c + 64];
        __builtin_amdgcn_sched_barrier(0);   // pin loads above the compute

        const float wr = __shfl(wt, r, 64);
        a0.x += wr * p0.x; a0.y += wr * p0.y; a0.z += wr * p0.z; a0.w += wr * p0.w;
        a1.x += wr * p1.x; a1.y += wr * p1.y; a1.z += wr * p1.z; a1.w += wr * p1.w;

        p0 = n0; p1 = n1;
    }

    // p holds row wmax == end row
    nt_store4(&out4[256 + c],      p0);
    nt_store4(&out4[256 + c + 64], p1);

    // weights are pre-normalized -> acc is the final attention output
    nt_store4(&out4[512 + c],      a0);
    nt_store4(&out4[512 + c + 64], a1);
}

extern "C" void kernel_launch(void* const* d_in, const int* in_sizes, int n_in,
                              void* d_out, int out_size, void* d_ws, size_t ws_size,
                              hipStream_t stream) {
    const float* emb    = (const float*)d_in[0];
    const int*   starts = (const int*)d_in[1];
    const int*   ends   = (const int*)d_in[2];
    const float* attn_w = (const float*)d_in[3];
    const float* attn_b = (const float*)d_in[4];
    float* out = (float*)d_out;

    int*   perm   = (int*)d_ws;                        // 4096 ints  = 16 KB
    float* scores = (float*)((int*)d_ws + NUM_SPANS);  // 8192 floats = 32 KB

    prep_kernel<<<513, 1024, 0, stream>>>(starts, emb, attn_w, attn_b, perm, scores);
    span_repr_kernel<<<NBLK2, 256, 0, stream>>>(emb, starts, ends, perm, scores, out);
}